// Round 6
// baseline (1125.178 us; speedup 1.0000x reference)
//
#include <hip/hip_runtime.h>
#include <hip/hip_bf16.h>

#define RES   100
#define ITERS 1000
#define SLOTP 128            // floats per LDS halo-row slot (512 B)

typedef float vf2 __attribute__((ext_vector_type(2)));

// ---------------- fused MLP layers 1-3 ----------------
__global__ __launch_bounds__(256) void mlp123(const float* __restrict__ pores,
                                              const float* __restrict__ W1, const float* __restrict__ b1,
                                              const float* __restrict__ W2, const float* __restrict__ b2,
                                              const float* __restrict__ W3, const float* __restrict__ b3,
                                              float* __restrict__ x3out) {
    __shared__ float x1[128];
    __shared__ float x2[256];
    const int s = blockIdx.x, tid = threadIdx.x;

    if (tid < 128) {
        float acc = b1[tid];
#pragma unroll
        for (int k = 0; k < 25; ++k)
            acc = fmaf(pores[s * 25 + k], W1[k * 128 + tid], acc);
        x1[tid] = fmaxf(acc, 0.0f);
    }
    __syncthreads();

    {
        float acc = b2[tid];
#pragma unroll 8
        for (int k = 0; k < 128; ++k)
            acc = fmaf(x1[k], W2[k * 256 + tid], acc);
        x2[tid] = fmaxf(acc, 0.0f);
    }
    __syncthreads();

    {
        float a0 = b3[tid], a1 = b3[tid + 256];
#pragma unroll 8
        for (int k = 0; k < 256; ++k) {
            float xv = x2[k];
            a0 = fmaf(xv, W3[k * 512 + tid],       a0);
            a1 = fmaf(xv, W3[k * 512 + tid + 256], a1);
        }
        x3out[s * 512 + tid]       = fmaxf(a0, 0.0f);
        x3out[s * 512 + tid + 256] = fmaxf(a1, 0.0f);
    }
}

// ---------------- layer 4: gen + residual + clamp, ILP-pipelined ----------------
__global__ __launch_bounds__(256) void fc4_fused(const float* __restrict__ X3,
                                                 const float* __restrict__ W4,
                                                 const float* __restrict__ b4,
                                                 const float* __restrict__ pores,
                                                 float* __restrict__ cond) {
    const int j = blockIdx.x * 256 + threadIdx.x;
    if (j >= RES * RES) return;
    const int bg = blockIdx.y;
    const float* x = X3 + bg * 8 * 512;

    float acc[8];
    float bj = b4[j];
#pragma unroll
    for (int b = 0; b < 8; ++b) acc[b] = bj;

    for (int k0 = 0; k0 < 512; k0 += 8) {
        float w[8];
#pragma unroll
        for (int u = 0; u < 8; ++u)
            w[u] = W4[(k0 + u) * (RES * RES) + j];
#pragma unroll
        for (int u = 0; u < 8; ++u) {
#pragma unroll
            for (int b = 0; b < 8; ++b)
                acc[b] = fmaf(x[b * 512 + k0 + u], w[u], acc[b]);
        }
    }

    const int row = j / RES, col = j % RES;
    const int p = (row / 20) * 5 + (col / 20);
#pragma unroll
    for (int b = 0; b < 8; ++b) {
        int bb = bg * 8 + b;
        float base = 1.0f - pores[bb * 25 + p];
        cond[bb * RES * RES + j] = fmaxf(acc[b] + base, 0.01f);
    }
}

// ---------------- Jacobi: DPP W/E + temporal blocking depth 2, 64KB LDS ----------------
// One WG (16 waves) per sample. Lane l owns cols (2l,2l+1); wave w owns rows
// [a, a+R), R=7 for w<4 else 6. Per superstep (2 Jacobi iters): read 2-row halos
// from each neighbor, compute extended band (iter t+1) register-only, then owned
// band (iter t+2), publish 4 halo rows, ONE barrier. Weights computed from global
// cond (one-time); no kst in LDS -> SA+SB = 64 KiB total (size proven in R2-R4).
// Halo slots: wave w -> 4w:row a, 4w+1:row a+1, 4w+2:row b-2, 4w+3:row b-1.

__device__ __forceinline__ float dpp_shr1(float old_v, float src) {  // lane i <- src[i-1]
    return __int_as_float(__builtin_amdgcn_update_dpp(
        __float_as_int(old_v), __float_as_int(src), 0x138, 0xf, 0xf, false));
}
__device__ __forceinline__ float dpp_shl1(float old_v, float src) {  // lane i <- src[i+1]
    return __int_as_float(__builtin_amdgcn_update_dpp(
        __float_as_int(old_v), __float_as_int(src), 0x130, 0xf, 0xf, false));
}

__device__ __forceinline__ vf2 rowstep(vf2 n, vf2 c, vf2 s,
                                       vf2 wn, vf2 ws, vf2 ww, vf2 we, bool fix49) {
    float lo = c.x, hi = c.y;
    float wlo = dpp_shr1(lo, hi);          // west of col 2l (lane0 -> self)
    float e   = dpp_shl1(hi, lo);          // east of col 2l+1
    float ehi = fix49 ? hi : e;            // col 99 mirror
    vf2 r;
    r.x = fmaf(wn.x, n.x, fmaf(ws.x, s.x, fmaf(ww.x, wlo, we.x * hi)));
    r.y = fmaf(wn.y, n.y, fmaf(ws.y, s.y, fmaf(we.y, ehi, ww.y * lo)));
    return r;
}

template<int R, bool TOP, bool BOT>
__device__ __forceinline__ void superstep(const float* __restrict__ srcN,
                                          const float* __restrict__ srcS,
                                          float* __restrict__ dst,
                                          const vf2* wN, const vf2* wS,
                                          const vf2* wW, const vf2* wE,
                                          vf2* T, bool fix49) {
    vf2 hN2, hN1, hS0, hS1;
    if (!TOP) {
        hN2 = *(const vf2*)(srcN);               // row a-2
        hN1 = *(const vf2*)(srcN + SLOTP);       // row a-1
    } else { hN1.x = 1.0f; hN1.y = 1.0f; hN2 = hN1; }
    if (!BOT) {
        hS0 = *(const vf2*)(srcS);               // row b
        hS1 = *(const vf2*)(srcS + SLOTP);       // row b+1
    } else { hS0.x = 0.0f; hS0.y = 0.0f; hS1 = hS0; }

    vf2 U[R + 2];                                // iter t+1 values, rows a-1 .. b
    if (TOP) { U[0].x = 1.0f; U[0].y = 1.0f; }
    else     U[0] = rowstep(hN2, hN1, T[0], wN[0], wS[0], wW[0], wE[0], fix49);
    U[1] = rowstep(hN1, T[0], T[1], wN[1], wS[1], wW[1], wE[1], fix49);
#pragma unroll
    for (int i = 2; i <= R - 1; ++i)
        U[i] = rowstep(T[i - 2], T[i - 1], T[i], wN[i], wS[i], wW[i], wE[i], fix49);
    U[R] = rowstep(T[R - 2], T[R - 1], hS0, wN[R], wS[R], wW[R], wE[R], fix49);
    if (BOT) { U[R + 1].x = 0.0f; U[R + 1].y = 0.0f; }
    else     U[R + 1] = rowstep(T[R - 1], hS0, hS1, wN[R + 1], wS[R + 1], wW[R + 1], wE[R + 1], fix49);

#pragma unroll
    for (int j = 0; j < R; ++j)                  // iter t+2, owned rows
        T[j] = rowstep(U[j], U[j + 1], U[j + 2], wN[j + 1], wS[j + 1], wW[j + 1], wE[j + 1], fix49);

    *(vf2*)(dst)             = T[0];
    *(vf2*)(dst + SLOTP)     = T[1];
    *(vf2*)(dst + 2 * SLOTP) = T[R - 2];
    *(vf2*)(dst + 3 * SLOTP) = T[R - 1];
}

__global__ __launch_bounds__(1024) void jacobi(const float* __restrict__ cond,
                                               float* __restrict__ kappa_out) {
    __shared__ float SA[64 * SLOTP];             // 32 KiB
    __shared__ float SB[64 * SLOTP];             // 32 KiB

    const int b   = blockIdx.x;
    const int tid = threadIdx.x;
    const float* condp = cond + b * RES * RES;

    const int w    = tid >> 6;
    const int lane = tid & 63;
    const int R    = (w < 4) ? 7 : 6;
    const int a    = (w < 4) ? 7 * w : 28 + 6 * (w - 4);
    const int c0   = min(2 * lane, 98), c1 = c0 + 1;
    const int lane2 = 2 * lane;
    const bool fix49 = (lane == 49);

    vf2 wN[9], wS[9], wW[9], wE[9], T[7];

    // weights straight from global cond (one-time, L2-resident)
#pragma unroll
    for (int i = 0; i < 9; ++i) {
        int row = a - 1 + i;
        if (i < R + 2 && row >= 0 && row < RES) {
            int in_ = row ? row - 1 : 0;
            int is_ = (row < RES - 1) ? row + 1 : RES - 1;
            int jw  = c0 ? c0 - 1 : 0;
            int je  = (c1 < RES - 1) ? c1 + 1 : RES - 1;
            float kc0 = condp[row * RES + c0], kc1 = condp[row * RES + c1];
            float kn0 = 0.5f * (kc0 + condp[in_ * RES + c0]);
            float kn1 = 0.5f * (kc1 + condp[in_ * RES + c1]);
            float ks0 = 0.5f * (kc0 + condp[is_ * RES + c0]);
            float ks1 = 0.5f * (kc1 + condp[is_ * RES + c1]);
            float kw0 = 0.5f * (kc0 + condp[row * RES + jw]);
            float kw1 = 0.5f * (kc1 + kc0);
            float ke0 = 0.5f * (kc0 + kc1);
            float ke1 = 0.5f * (kc1 + condp[row * RES + je]);
            float inv0 = 1.0f / (kn0 + ks0 + kw0 + ke0 + 1e-12f);
            float inv1 = 1.0f / (kn1 + ks1 + kw1 + ke1 + 1e-12f);
            wN[i].x = kn0 * inv0;  wN[i].y = kn1 * inv1;
            wS[i].x = ks0 * inv0;  wS[i].y = ks1 * inv1;
            wW[i].x = kw0 * inv0;  wW[i].y = kw1 * inv1;
            wE[i].x = ke0 * inv0;  wE[i].y = ke1 * inv1;
        }
    }

#pragma unroll
    for (int j = 0; j < 7; ++j)
        if (j < R) {
            float v = 1.0f - (float)(a + j) * (1.0f / (RES - 1));
            T[j].x = v;  T[j].y = v;
        }

    // halo pointers (clamped so no OOB address is ever formed)
    const int nb = (w > 0)  ? (4 * w - 2) : 0;
    const int sb = (w < 15) ? (4 * w + 4) : 60;
    const float* SAn = SA + lane2 + nb * SLOTP;
    const float* SAs = SA + lane2 + sb * SLOTP;
    float*       SAd = SA + lane2 + (4 * w) * SLOTP;
    const float* SBn = SB + lane2 + nb * SLOTP;
    const float* SBs = SB + lane2 + sb * SLOTP;
    float*       SBd = SB + lane2 + (4 * w) * SLOTP;

    // initial publish (state t=0) into SA
    *(vf2*)(SAd)             = T[0];
    *(vf2*)(SAd + SLOTP)     = T[1];
    *(vf2*)(SAd + 2 * SLOTP) = T[R - 2];
    *(vf2*)(SAd + 3 * SLOTP) = T[R - 1];
    __syncthreads();

    for (int it = 0; it < ITERS / 4; ++it) {     // 250 x (2 supersteps x 2 iters) = 1000
        if (w == 0)      superstep<7, true,  false>(SAn, SAs, SBd, wN, wS, wW, wE, T, fix49);
        else if (w < 4)  superstep<7, false, false>(SAn, SAs, SBd, wN, wS, wW, wE, T, fix49);
        else if (w < 15) superstep<6, false, false>(SAn, SAs, SBd, wN, wS, wW, wE, T, fix49);
        else             superstep<6, false, true >(SAn, SAs, SBd, wN, wS, wW, wE, T, fix49);
        __syncthreads();
        if (w == 0)      superstep<7, true,  false>(SBn, SBs, SAd, wN, wS, wW, wE, T, fix49);
        else if (w < 4)  superstep<7, false, false>(SBn, SBs, SAd, wN, wS, wW, wE, T, fix49);
        else if (w < 15) superstep<6, false, false>(SBn, SBs, SAd, wN, wS, wW, wE, T, fix49);
        else             superstep<6, false, true >(SBn, SBs, SAd, wN, wS, wW, wE, T, fix49);
        __syncthreads();
    }

    // kappa = mean_j 2*res*k[0][j]*(1 - T[0][j]) = 2 * sum_lanes k*(1-T)
    if (w == 0) {
        float s = 0.0f;
        if (lane < 50)
            s = condp[c0] * (1.0f - T[0].x) + condp[c1] * (1.0f - T[0].y);
        for (int off = 32; off; off >>= 1)
            s += __shfl_down(s, off);
        if (lane == 0) kappa_out[b] = 2.0f * s;
    }
}

extern "C" void kernel_launch(void* const* d_in, const int* in_sizes, int n_in,
                              void* d_out, int out_size, void* d_ws, size_t ws_size,
                              hipStream_t stream) {
    (void)in_sizes; (void)n_in; (void)out_size; (void)ws_size;
    const float* pores = (const float*)d_in[0];
    const float* W1 = (const float*)d_in[1];
    const float* b1 = (const float*)d_in[2];
    const float* W2 = (const float*)d_in[3];
    const float* b2 = (const float*)d_in[4];
    const float* W3 = (const float*)d_in[5];
    const float* b3 = (const float*)d_in[6];
    const float* W4 = (const float*)d_in[7];
    const float* b4 = (const float*)d_in[8];

    float* x3 = (float*)d_ws;               // 32*512

    float* kappa = (float*)d_out;           // 32
    float* cond  = kappa + 32;              // 32*100*100

    mlp123<<<32, 256, 0, stream>>>(pores, W1, b1, W2, b2, W3, b3, x3);
    fc4_fused<<<dim3(40, 4), 256, 0, stream>>>(x3, W4, b4, pores, cond);
    jacobi<<<32, 1024, 0, stream>>>(cond, kappa);
}

// Round 7
// 1093.638 us; speedup vs baseline: 1.0288x; 1.0288x over previous
//
#include <hip/hip_runtime.h>
#include <hip/hip_bf16.h>

#define RES   100
#define ITERS 1000
#define SLOTP 128            // floats per LDS halo-row slot (512 B)

typedef float vf2 __attribute__((ext_vector_type(2)));

// ---------------- fused MLP layers 1-3 ----------------
__global__ __launch_bounds__(256) void mlp123(const float* __restrict__ pores,
                                              const float* __restrict__ W1, const float* __restrict__ b1,
                                              const float* __restrict__ W2, const float* __restrict__ b2,
                                              const float* __restrict__ W3, const float* __restrict__ b3,
                                              float* __restrict__ x3out) {
    __shared__ float x1[128];
    __shared__ float x2[256];
    const int s = blockIdx.x, tid = threadIdx.x;

    if (tid < 128) {
        float acc = b1[tid];
#pragma unroll
        for (int k = 0; k < 25; ++k)
            acc = fmaf(pores[s * 25 + k], W1[k * 128 + tid], acc);
        x1[tid] = fmaxf(acc, 0.0f);
    }
    __syncthreads();

    {
        float acc = b2[tid];
#pragma unroll 8
        for (int k = 0; k < 128; ++k)
            acc = fmaf(x1[k], W2[k * 256 + tid], acc);
        x2[tid] = fmaxf(acc, 0.0f);
    }
    __syncthreads();

    {
        float a0 = b3[tid], a1 = b3[tid + 256];
#pragma unroll 8
        for (int k = 0; k < 256; ++k) {
            float xv = x2[k];
            a0 = fmaf(xv, W3[k * 512 + tid],       a0);
            a1 = fmaf(xv, W3[k * 512 + tid + 256], a1);
        }
        x3out[s * 512 + tid]       = fmaxf(a0, 0.0f);
        x3out[s * 512 + tid + 256] = fmaxf(a1, 0.0f);
    }
}

// ---------------- layer 4: gen + residual + clamp, ILP-pipelined ----------------
__global__ __launch_bounds__(256) void fc4_fused(const float* __restrict__ X3,
                                                 const float* __restrict__ W4,
                                                 const float* __restrict__ b4,
                                                 const float* __restrict__ pores,
                                                 float* __restrict__ cond) {
    const int j = blockIdx.x * 256 + threadIdx.x;
    if (j >= RES * RES) return;
    const int bg = blockIdx.y;
    const float* x = X3 + bg * 8 * 512;

    float acc[8];
    float bj = b4[j];
#pragma unroll
    for (int b = 0; b < 8; ++b) acc[b] = bj;

    for (int k0 = 0; k0 < 512; k0 += 8) {
        float w[8];
#pragma unroll
        for (int u = 0; u < 8; ++u)
            w[u] = W4[(k0 + u) * (RES * RES) + j];
#pragma unroll
        for (int u = 0; u < 8; ++u) {
#pragma unroll
            for (int b = 0; b < 8; ++b)
                acc[b] = fmaf(x[b * 512 + k0 + u], w[u], acc[b]);
        }
    }

    const int row = j / RES, col = j % RES;
    const int p = (row / 20) * 5 + (col / 20);
#pragma unroll
    for (int b = 0; b < 8; ++b) {
        int bb = bg * 8 + b;
        float base = 1.0f - pores[bb * 25 + p];
        cond[bb * RES * RES + j] = fmaxf(acc[b] + base, 0.01f);
    }
}

// ---------------- Jacobi: DPP W/E + temporal depth 2, rolling-U, 128 VGPR ----------------
__device__ __forceinline__ float dpp_shr1(float old_v, float src) {  // lane i <- src[i-1]
    return __int_as_float(__builtin_amdgcn_update_dpp(
        __float_as_int(old_v), __float_as_int(src), 0x138, 0xf, 0xf, false));
}
__device__ __forceinline__ float dpp_shl1(float old_v, float src) {  // lane i <- src[i+1]
    return __int_as_float(__builtin_amdgcn_update_dpp(
        __float_as_int(old_v), __float_as_int(src), 0x130, 0xf, 0xf, false));
}

__device__ __forceinline__ vf2 rowstep(vf2 n, vf2 c, vf2 s,
                                       vf2 wn, vf2 ws, vf2 ww, vf2 we, bool fix49) {
    float lo = c.x, hi = c.y;
    float wlo = dpp_shr1(lo, hi);          // west of col 2l (lane0 -> self)
    float e   = dpp_shl1(hi, lo);          // east of col 2l+1
    float ehi = fix49 ? hi : e;            // col 99 mirror
    vf2 r;
    r.x = fmaf(wn.x, n.x, fmaf(ws.x, s.x, fmaf(ww.x, wlo, we.x * hi)));
    r.y = fmaf(wn.y, n.y, fmaf(ws.y, s.y, fmaf(we.y, ehi, ww.y * lo)));
    return r;
}

// Superstep = 2 Jacobi iters, one barrier (caller). Rolling 3-wide U window:
// U[i] = iter t+1 value of row a-1+i (weights idx i); T[j] = owned row a+j.
// Order guarantees U[j+2] (which reads T[j]) is computed before T[j] is overwritten.
template<int R, bool TOP, bool BOT>
__device__ __forceinline__ void superstep(const float* __restrict__ srcN,
                                          const float* __restrict__ srcS,
                                          float* __restrict__ dst,
                                          const vf2* wN, const vf2* wS,
                                          const vf2* wW, const vf2* wE,
                                          vf2* T, bool fix49) {
    vf2 hN2, hN1, hS0, hS1;
    if (!TOP) {
        hN2 = *(const vf2*)(srcN);               // row a-2
        hN1 = *(const vf2*)(srcN + SLOTP);       // row a-1
    } else { hN1.x = 1.0f; hN1.y = 1.0f; hN2 = hN1; }
    if (!BOT) {
        hS0 = *(const vf2*)(srcS);               // row b
        hS1 = *(const vf2*)(srcS + SLOTP);       // row b+1
    } else { hS0.x = 0.0f; hS0.y = 0.0f; hS1 = hS0; }

    vf2 u0, u1, u2;
    if (TOP) { u0.x = 1.0f; u0.y = 1.0f; }
    else     u0 = rowstep(hN2, hN1, T[0], wN[0], wS[0], wW[0], wE[0], fix49);
    u1 = rowstep(hN1, T[0], T[1], wN[1], wS[1], wW[1], wE[1], fix49);

#pragma unroll
    for (int j = 0; j < R; ++j) {
        if (j + 2 <= R - 1)
            u2 = rowstep(T[j], T[j + 1], T[j + 2], wN[j + 2], wS[j + 2], wW[j + 2], wE[j + 2], fix49);
        else if (j + 2 == R)
            u2 = rowstep(T[R - 2], T[R - 1], hS0, wN[R], wS[R], wW[R], wE[R], fix49);
        else {                                   // j + 2 == R + 1
            if (BOT) { u2.x = 0.0f; u2.y = 0.0f; }
            else     u2 = rowstep(T[R - 1], hS0, hS1, wN[R + 1], wS[R + 1], wW[R + 1], wE[R + 1], fix49);
        }
        T[j] = rowstep(u0, u1, u2, wN[j + 1], wS[j + 1], wW[j + 1], wE[j + 1], fix49);
        u0 = u1;  u1 = u2;
    }

    *(vf2*)(dst)             = T[0];
    *(vf2*)(dst + SLOTP)     = T[1];
    *(vf2*)(dst + 2 * SLOTP) = T[R - 2];
    *(vf2*)(dst + 3 * SLOTP) = T[R - 1];
}

__global__ __launch_bounds__(1024, 4) void jacobi(const float* __restrict__ cond,
                                                  float* __restrict__ kappa_out) {
    __shared__ float SA[64 * SLOTP];             // 32 KiB
    __shared__ float SB[64 * SLOTP];             // 32 KiB

    const int b   = blockIdx.x;
    const int tid = threadIdx.x;
    const float* condp = cond + b * RES * RES;

    const int w    = tid >> 6;
    const int lane = tid & 63;
    const int R    = (w < 4) ? 7 : 6;
    const int a    = (w < 4) ? 7 * w : 28 + 6 * (w - 4);
    const int c0   = min(2 * lane, 98), c1 = c0 + 1;
    const int lane2 = 2 * lane;
    const bool fix49 = (lane == 49);

    vf2 wN[9], wS[9], wW[9], wE[9], T[7];

    // weights straight from global cond (one-time, L2-resident)
#pragma unroll
    for (int i = 0; i < 9; ++i) {
        int row = a - 1 + i;
        if (i < R + 2 && row >= 0 && row < RES) {
            int in_ = row ? row - 1 : 0;
            int is_ = (row < RES - 1) ? row + 1 : RES - 1;
            int jw  = c0 ? c0 - 1 : 0;
            int je  = (c1 < RES - 1) ? c1 + 1 : RES - 1;
            float kc0 = condp[row * RES + c0], kc1 = condp[row * RES + c1];
            float kn0 = 0.5f * (kc0 + condp[in_ * RES + c0]);
            float kn1 = 0.5f * (kc1 + condp[in_ * RES + c1]);
            float ks0 = 0.5f * (kc0 + condp[is_ * RES + c0]);
            float ks1 = 0.5f * (kc1 + condp[is_ * RES + c1]);
            float kw0 = 0.5f * (kc0 + condp[row * RES + jw]);
            float kw1 = 0.5f * (kc1 + kc0);
            float ke0 = 0.5f * (kc0 + kc1);
            float ke1 = 0.5f * (kc1 + condp[row * RES + je]);
            float inv0 = 1.0f / (kn0 + ks0 + kw0 + ke0 + 1e-12f);
            float inv1 = 1.0f / (kn1 + ks1 + kw1 + ke1 + 1e-12f);
            wN[i].x = kn0 * inv0;  wN[i].y = kn1 * inv1;
            wS[i].x = ks0 * inv0;  wS[i].y = ks1 * inv1;
            wW[i].x = kw0 * inv0;  wW[i].y = kw1 * inv1;
            wE[i].x = ke0 * inv0;  wE[i].y = ke1 * inv1;
        }
    }

#pragma unroll
    for (int j = 0; j < 7; ++j)
        if (j < R) {
            float v = 1.0f - (float)(a + j) * (1.0f / (RES - 1));
            T[j].x = v;  T[j].y = v;
        }

    // halo pointers (clamped so no OOB address is ever formed)
    const int nb = (w > 0)  ? (4 * w - 2) : 0;
    const int sb = (w < 15) ? (4 * w + 4) : 60;
    const float* SAn = SA + lane2 + nb * SLOTP;
    const float* SAs = SA + lane2 + sb * SLOTP;
    float*       SAd = SA + lane2 + (4 * w) * SLOTP;
    const float* SBn = SB + lane2 + nb * SLOTP;
    const float* SBs = SB + lane2 + sb * SLOTP;
    float*       SBd = SB + lane2 + (4 * w) * SLOTP;

    // initial publish (state t=0) into SA
    *(vf2*)(SAd)             = T[0];
    *(vf2*)(SAd + SLOTP)     = T[1];
    *(vf2*)(SAd + 2 * SLOTP) = T[R - 2];
    *(vf2*)(SAd + 3 * SLOTP) = T[R - 1];
    __syncthreads();

    for (int it = 0; it < ITERS / 4; ++it) {     // 250 x (2 supersteps x 2 iters) = 1000
        if (w == 0)      superstep<7, true,  false>(SAn, SAs, SBd, wN, wS, wW, wE, T, fix49);
        else if (w < 4)  superstep<7, false, false>(SAn, SAs, SBd, wN, wS, wW, wE, T, fix49);
        else if (w < 15) superstep<6, false, false>(SAn, SAs, SBd, wN, wS, wW, wE, T, fix49);
        else             superstep<6, false, true >(SAn, SAs, SBd, wN, wS, wW, wE, T, fix49);
        __syncthreads();
        if (w == 0)      superstep<7, true,  false>(SBn, SBs, SAd, wN, wS, wW, wE, T, fix49);
        else if (w < 4)  superstep<7, false, false>(SBn, SBs, SAd, wN, wS, wW, wE, T, fix49);
        else if (w < 15) superstep<6, false, false>(SBn, SBs, SAd, wN, wS, wW, wE, T, fix49);
        else             superstep<6, false, true >(SBn, SBs, SAd, wN, wS, wW, wE, T, fix49);
        __syncthreads();
    }

    // kappa = mean_j 2*res*k[0][j]*(1 - T[0][j]) = 2 * sum_lanes k*(1-T)
    if (w == 0) {
        float s = 0.0f;
        if (lane < 50)
            s = condp[c0] * (1.0f - T[0].x) + condp[c1] * (1.0f - T[0].y);
        for (int off = 32; off; off >>= 1)
            s += __shfl_down(s, off);
        if (lane == 0) kappa_out[b] = 2.0f * s;
    }
}

extern "C" void kernel_launch(void* const* d_in, const int* in_sizes, int n_in,
                              void* d_out, int out_size, void* d_ws, size_t ws_size,
                              hipStream_t stream) {
    (void)in_sizes; (void)n_in; (void)out_size; (void)ws_size;
    const float* pores = (const float*)d_in[0];
    const float* W1 = (const float*)d_in[1];
    const float* b1 = (const float*)d_in[2];
    const float* W2 = (const float*)d_in[3];
    const float* b2 = (const float*)d_in[4];
    const float* W3 = (const float*)d_in[5];
    const float* b3 = (const float*)d_in[6];
    const float* W4 = (const float*)d_in[7];
    const float* b4 = (const float*)d_in[8];

    float* x3 = (float*)d_ws;               // 32*512

    float* kappa = (float*)d_out;           // 32
    float* cond  = kappa + 32;              // 32*100*100

    mlp123<<<32, 256, 0, stream>>>(pores, W1, b1, W2, b2, W3, b3, x3);
    fc4_fused<<<dim3(40, 4), 256, 0, stream>>>(x3, W4, b4, pores, cond);
    jacobi<<<32, 1024, 0, stream>>>(cond, kappa);
}